// Round 4
// baseline (498.045 us; speedup 1.0000x reference)
//
#include <hip/hip_runtime.h>

typedef unsigned short u16;
typedef __attribute__((ext_vector_type(8))) short bf16x8;     // MFMA A/B frag (8 bf16)
typedef __attribute__((ext_vector_type(4))) float floatx4;    // MFMA C/D frag
typedef __attribute__((ext_vector_type(8))) unsigned short u16x8;
typedef __attribute__((ext_vector_type(4))) unsigned short u16x4;

#define NTOK 4096
#define DDIN 512
#define DDOUT 512
#define NP 8

__device__ __forceinline__ float b2f(u16 b) {
    union { unsigned int u; float f; } v; v.u = ((unsigned int)b) << 16; return v.f;
}
__device__ __forceinline__ u16 f2b(float f) {
    union { float f; unsigned int u; } v; v.f = f;
    unsigned int r = (v.u + 0x7fffu + ((v.u >> 16) & 1u)) >> 16;
    return (u16)r;
}
__device__ __forceinline__ float sp(float x) {
    return fmaxf(x, 0.f) + __logf(1.f + __expf(-fabsf(x)));
}
__device__ __forceinline__ float sigm(float x) { return 1.f / (1.f + __expf(-x)); }

__device__ __forceinline__ void gld16(const u16* g, u16* l) {
    __builtin_amdgcn_global_load_lds((const __attribute__((address_space(1))) void*)g,
                                     (__attribute__((address_space(3))) void*)l, 16, 0, 0);
}

__global__ void prep_sqsp(const float* __restrict__ in, u16* __restrict__ out, int n) {
    int i = blockIdx.x * 256 + threadIdx.x;
    if (i < n) {
        float s = sp(in[i]);
        out[i] = f2b(s * s);
    }
}

// zwT[p][e][c] = zw[p][c][e] + zw[p][c+512][e]
__global__ void prep_zwT(const float* __restrict__ zw, u16* __restrict__ zwT) {
    int p = blockIdx.z;
    int c0 = blockIdx.x * 32, e0 = blockIdx.y * 32;
    __shared__ float tb[32][33];
    int tx = threadIdx.x, ty = threadIdx.y; // 32 x 8
    const float* base = zw + (size_t)p * 1024 * 512;
#pragma unroll
    for (int r = 0; r < 4; ++r) {
        int cl = ty * 4 + r;
        float a = base[(size_t)(c0 + cl) * 512 + e0 + tx];
        float b = base[(size_t)(c0 + cl + 512) * 512 + e0 + tx];
        tb[cl][tx] = a + b;
    }
    __syncthreads();
    u16* outb = zwT + (size_t)p * 512 * 512;
#pragma unroll
    for (int r = 0; r < 4; ++r) {
        int el = ty * 4 + r;
        outb[(size_t)(e0 + el) * 512 + c0 + tx] = f2b(tb[tx][el]);
    }
}

// phi expansion + bf16 copy of x
__global__ void phi_kernel(const float* __restrict__ x, u16* __restrict__ phi,
                           u16* __restrict__ xb) {
    int i = blockIdx.x * 256 + threadIdx.x;
    float xv = x[i];
    xb[i] = f2b(xv);
    u16x8 v;
#pragma unroll
    for (int k = 0; k < 8; ++k) {
        float s = -1.f + (2.f / 7.f) * (float)k;
        v[k] = f2b(sp(xv + s));
    }
    *(u16x8*)(phi + (size_t)i * 8) = v;
}

// GEMM1 partial, split-K=8 (kc pinned to XCD). 128x128 tile, BK=64.
// Partials stored bf16 in d_out scratch: xpart[kc][n][o].
__launch_bounds__(256, 4)
__global__ void gemm1p(const u16* __restrict__ phi, const u16* __restrict__ wphi,
                       u16* __restrict__ xpart) {
    __shared__ __align__(16) u16 lds[2 * 8192];
    u16* As = lds;          // [128][64]
    u16* Bs = lds + 8192;

    const int id = blockIdx.x;
    const int kc = id & 7;                 // XCD-pinned K-chunk
    const int local = id >> 3;             // [0,128)
    const int o0 = (local & 3) * 128;
    const int n0 = (local >> 2) * 128;
    const int kbase = kc * 512;

    const int t = threadIdx.x;
    const int wave = t >> 6, lane = t & 63;
    const int wm = wave >> 1, wn = wave & 1;
    const int l15 = lane & 15, quad = lane >> 4;
    const int srow = t >> 3, scol = (t & 7) * 8;

    floatx4 acc[4][4];
#pragma unroll
    for (int i = 0; i < 4; ++i)
#pragma unroll
        for (int j = 0; j < 4; ++j) acc[i][j] = {0.f, 0.f, 0.f, 0.f};

    for (int k0 = 0; k0 < 512; k0 += 64) {
        const u16* ga = phi + (size_t)(n0 + srow) * 4096 + kbase + k0 + scol;
        const u16* gb = wphi + (size_t)(o0 + srow) * 4096 + kbase + k0 + scol;
        __syncthreads();
#pragma unroll
        for (int c = 0; c < 4; ++c) {
            gld16(ga + (size_t)c * 32 * 4096, As + c * 2048 + t * 8);
            gld16(gb + (size_t)c * 32 * 4096, Bs + c * 2048 + t * 8);
        }
        __syncthreads();
#pragma unroll
        for (int ks = 0; ks < 2; ++ks) {
            bf16x8 a[4], b[4];
#pragma unroll
            for (int s = 0; s < 4; ++s) {
                a[s] = *(const bf16x8*)(As + (wm * 64 + s * 16 + l15) * 64 + ks * 32 + quad * 8);
                b[s] = *(const bf16x8*)(Bs + (wn * 64 + s * 16 + l15) * 64 + ks * 32 + quad * 8);
            }
#pragma unroll
            for (int sm = 0; sm < 4; ++sm)
#pragma unroll
                for (int sn = 0; sn < 4; ++sn)
                    acc[sm][sn] = __builtin_amdgcn_mfma_f32_16x16x32_bf16(a[sm], b[sn], acc[sm][sn], 0, 0, 0);
        }
    }

    u16* xp = xpart + (size_t)kc * NTOK * DDOUT;
#pragma unroll
    for (int sm = 0; sm < 4; ++sm)
#pragma unroll
        for (int sn = 0; sn < 4; ++sn) {
            int gcol = o0 + wn * 64 + sn * 16 + l15;
#pragma unroll
            for (int r = 0; r < 4; ++r) {
                int grow = n0 + wm * 64 + sm * 16 + quad * 4 + r;
                xp[(size_t)grow * DDOUT + gcol] = f2b(acc[sm][sn][r]);
            }
        }
}

// reduce 8 bf16 partials + phi_bias, expand 8 gated softplus planes -> z0 (bf16)
__global__ void reduce_ep(const u16* __restrict__ xpart, const float* __restrict__ phi_bias,
                          const float* __restrict__ gate_raw, u16* __restrict__ z0) {
    int idx = blockIdx.x * 256 + threadIdx.x;      // 524288 threads, 4 elems each
    int n = idx >> 7;
    int o4 = (idx & 127) * 4;
    size_t base = (size_t)n * DDOUT + o4;
    float s0 = 0.f, s1 = 0.f, s2 = 0.f, s3 = 0.f;
#pragma unroll
    for (int kc = 0; kc < 8; ++kc) {
        u16x4 v = *(const u16x4*)(xpart + (size_t)kc * NTOK * DDOUT + base);
        s0 += b2f(v[0]); s1 += b2f(v[1]); s2 += b2f(v[2]); s3 += b2f(v[3]);
    }
    floatx4 pb = *(const floatx4*)(phi_bias + o4);
    s0 += pb[0]; s1 += pb[1]; s2 += pb[2]; s3 += pb[3];
#pragma unroll
    for (int p = 0; p < NP; ++p) {
        float g = sigm(gate_raw[p]);
        u16x4 v;
        v[0] = f2b(sp(s0 * g)); v[1] = f2b(sp(s1 * g));
        v[2] = f2b(sp(s2 * g)); v[3] = f2b(sp(s3 * g));
        *(u16x4*)(z0 + (size_t)p * NTOK * DDOUT + base) = v;
    }
}

// Fused GEMM2+GEMM3, 128x128 tile, BK=32 (32 KB LDS -> 4 blocks/CU), dual acc.
// XCD-pinned: p = blockIdx.x & 7.
__launch_bounds__(256, 4)
__global__ void gemm23(const u16* __restrict__ z0, const u16* __restrict__ w2b,
                       const u16* __restrict__ xb, const u16* __restrict__ zwT,
                       const float* __restrict__ bias2, const float* __restrict__ gate_raw2,
                       const float* __restrict__ output_bias, float* __restrict__ out) {
    __shared__ __align__(16) u16 lds[4 * 4096];   // 32 KB
    u16* A1 = lds;              // z0 tile [128][32]
    u16* B1 = lds + 4096;       // w2 tile
    u16* A2 = lds + 8192;       // xb tile
    u16* B2 = lds + 12288;      // zwT tile

    const int id = blockIdx.x;
    const int p = id & 7;
    const int local = id >> 3;                 // [0,128)
    const int e0 = (local & 3) * 128;
    const int n0 = (local >> 2) * 128;

    const int t = threadIdx.x;
    const int wave = t >> 6, lane = t & 63;
    const int wm = wave >> 1, wn = wave & 1;
    const int l15 = lane & 15, quad = lane >> 4;
    const int srow = t >> 2, scol = (t & 3) * 8;   // 64 rows per gld16 round

    const u16* z0p = z0 + (size_t)p * NTOK * DDOUT;
    const u16* w2p = w2b + (size_t)p * DDOUT * DDOUT;
    const u16* zwp = zwT + (size_t)p * DDOUT * DDIN;

    floatx4 acc1[4][4], acc2[4][4];
#pragma unroll
    for (int i = 0; i < 4; ++i)
#pragma unroll
        for (int j = 0; j < 4; ++j) {
            acc1[i][j] = {0.f, 0.f, 0.f, 0.f};
            acc2[i][j] = {0.f, 0.f, 0.f, 0.f};
        }

    for (int k0 = 0; k0 < 512; k0 += 32) {
        const u16* ga1 = z0p + (size_t)(n0 + srow) * 512 + k0 + scol;
        const u16* gb1 = w2p + (size_t)(e0 + srow) * 512 + k0 + scol;
        const u16* ga2 = xb  + (size_t)(n0 + srow) * 512 + k0 + scol;
        const u16* gb2 = zwp + (size_t)(e0 + srow) * 512 + k0 + scol;
        __syncthreads();
#pragma unroll
        for (int c = 0; c < 2; ++c) {
            gld16(ga1 + (size_t)c * 64 * 512, A1 + c * 2048 + t * 8);
            gld16(gb1 + (size_t)c * 64 * 512, B1 + c * 2048 + t * 8);
            gld16(ga2 + (size_t)c * 64 * 512, A2 + c * 2048 + t * 8);
            gld16(gb2 + (size_t)c * 64 * 512, B2 + c * 2048 + t * 8);
        }
        __syncthreads();
        bf16x8 a1[4], b1[4], a2[4], b2[4];
#pragma unroll
        for (int s = 0; s < 4; ++s) {
            int ro = (wm * 64 + s * 16 + l15) * 32 + quad * 8;
            int co = (wn * 64 + s * 16 + l15) * 32 + quad * 8;
            a1[s] = *(const bf16x8*)(A1 + ro);
            b1[s] = *(const bf16x8*)(B1 + co);
            a2[s] = *(const bf16x8*)(A2 + ro);
            b2[s] = *(const bf16x8*)(B2 + co);
        }
#pragma unroll
        for (int sm = 0; sm < 4; ++sm)
#pragma unroll
            for (int sn = 0; sn < 4; ++sn) {
                acc1[sm][sn] = __builtin_amdgcn_mfma_f32_16x16x32_bf16(a1[sm], b1[sn], acc1[sm][sn], 0, 0, 0);
                acc2[sm][sn] = __builtin_amdgcn_mfma_f32_16x16x32_bf16(a2[sm], b2[sn], acc2[sm][sn], 0, 0, 0);
            }
    }

    const float g2p = sigm(gate_raw2[p]);
#pragma unroll
    for (int sm = 0; sm < 4; ++sm)
#pragma unroll
        for (int sn = 0; sn < 4; ++sn) {
            int gcol = e0 + wn * 64 + sn * 16 + l15;
            float bb = bias2[p * DDOUT + gcol];
            float ob = output_bias[p * DDOUT + gcol];
#pragma unroll
            for (int r = 0; r < 4; ++r) {
                int grow = n0 + wm * 64 + sm * 16 + quad * 4 + r;
                float v1 = acc1[sm][sn][r] + bb;
                float o = sp(sp(v1 * g2p) + acc2[sm][sn][r]) + ob;
                out[(size_t)grow * (NP * DDOUT) + p * DDOUT + gcol] = o;
            }
        }
}

extern "C" void kernel_launch(void* const* d_in, const int* in_sizes, int n_in,
                              void* d_out, int out_size, void* d_ws, size_t ws_size,
                              hipStream_t stream) {
    const float* x           = (const float*)d_in[0];
    const float* phi_raw     = (const float*)d_in[1];
    const float* phi_bias    = (const float*)d_in[2];
    const float* raw_weight2 = (const float*)d_in[3];
    const float* bias2       = (const float*)d_in[4];
    const float* gate_raw2   = (const float*)d_in[5];
    const float* z_weight    = (const float*)d_in[6];
    const float* gate_raw    = (const float*)d_in[7];
    const float* output_bias = (const float*)d_in[8];
    float* out = (float*)d_out;

    u16* ws   = (u16*)d_ws;
    u16* phi  = ws;                                  // 4096*4096 bf16
    u16* wphi = phi + (size_t)4096 * 4096;           // 512*4096
    u16* w2b  = wphi + (size_t)512 * 4096;           // 8*512*512
    u16* zwT  = w2b + (size_t)8 * 512 * 512;         // 8*512*512
    u16* z0   = zwT + (size_t)8 * 512 * 512;         // 8*4096*512
    u16* xb   = z0 + (size_t)8 * 4096 * 512;         // 4096*512
    // split-K=8 bf16 partials in d_out (33.5 MB of 67 MB), consumed by
    // reduce_ep before gemm23 overwrites d_out with the real fp32 output.
    u16* xpart = (u16*)d_out;

    hipLaunchKernelGGL(prep_sqsp, dim3(8192), dim3(256), 0, stream, phi_raw, wphi, 512 * 4096);
    hipLaunchKernelGGL(prep_sqsp, dim3(8192), dim3(256), 0, stream, raw_weight2, w2b, 8 * 512 * 512);
    hipLaunchKernelGGL(prep_zwT, dim3(16, 16, 8), dim3(32, 8), 0, stream, z_weight, zwT);
    hipLaunchKernelGGL(phi_kernel, dim3(8192), dim3(256), 0, stream, x, phi, xb);
    hipLaunchKernelGGL(gemm1p, dim3(1024), dim3(256), 0, stream, phi, wphi, xpart);
    hipLaunchKernelGGL(reduce_ep, dim3(2048), dim3(256), 0, stream, xpart, phi_bias, gate_raw, z0);
    hipLaunchKernelGGL(gemm23, dim3(1024), dim3(256), 0, stream,
                       z0, w2b, xb, zwT, bias2, gate_raw2, output_bias, out);
}

// Round 5
// 217.614 us; speedup vs baseline: 2.2887x; 2.2887x over previous
//
#include <hip/hip_runtime.h>

typedef unsigned short u16;
typedef __attribute__((ext_vector_type(8))) short bf16x8;     // MFMA A/B frag (8 bf16)
typedef __attribute__((ext_vector_type(4))) float floatx4;    // MFMA C/D frag
typedef __attribute__((ext_vector_type(8))) unsigned short u16x8;
typedef __attribute__((ext_vector_type(4))) unsigned short u16x4;

#define NTOK 4096
#define DDIN 512
#define DDOUT 512
#define NP 8

__device__ __forceinline__ float b2f(u16 b) {
    union { unsigned int u; float f; } v; v.u = ((unsigned int)b) << 16; return v.f;
}
__device__ __forceinline__ u16 f2b(float f) {
    union { float f; unsigned int u; } v; v.f = f;
    unsigned int r = (v.u + 0x7fffu + ((v.u >> 16) & 1u)) >> 16;
    return (u16)r;
}
__device__ __forceinline__ float sp(float x) {
    return fmaxf(x, 0.f) + __logf(1.f + __expf(-fabsf(x)));
}
__device__ __forceinline__ float sigm(float x) { return 1.f / (1.f + __expf(-x)); }

__device__ __forceinline__ void gld16(const u16* g, u16* l) {
    __builtin_amdgcn_global_load_lds((const __attribute__((address_space(1))) void*)g,
                                     (__attribute__((address_space(3))) void*)l, 16, 0, 0);
}

// weight transform for both phi_raw and raw_weight2 in one launch:
// out[i] = bf16( softplus(in[i])^2 )
__global__ void prep_sqsp2(const float* __restrict__ in1, u16* __restrict__ out1, int n1,
                           const float* __restrict__ in2, u16* __restrict__ out2, int n2) {
    int i = blockIdx.x * 256 + threadIdx.x;
    if (i < n1) {
        float s = sp(in1[i]);
        out1[i] = f2b(s * s);
    } else if (i - n1 < n2) {
        int j = i - n1;
        float s = sp(in2[j]);
        out2[j] = f2b(s * s);
    }
}

// zwT[p][e][c] = zw[p][c][e] + zw[p][c+512][e]
__global__ void prep_zwT(const float* __restrict__ zw, u16* __restrict__ zwT) {
    int p = blockIdx.z;
    int c0 = blockIdx.x * 32, e0 = blockIdx.y * 32;
    __shared__ float tb[32][33];
    int tx = threadIdx.x, ty = threadIdx.y; // 32 x 8
    const float* base = zw + (size_t)p * 1024 * 512;
#pragma unroll
    for (int r = 0; r < 4; ++r) {
        int cl = ty * 4 + r;
        float a = base[(size_t)(c0 + cl) * 512 + e0 + tx];
        float b = base[(size_t)(c0 + cl + 512) * 512 + e0 + tx];
        tb[cl][tx] = a + b;
    }
    __syncthreads();
    u16* outb = zwT + (size_t)p * 512 * 512;
#pragma unroll
    for (int r = 0; r < 4; ++r) {
        int el = ty * 4 + r;
        outb[(size_t)(e0 + el) * 512 + c0 + tx] = f2b(tb[tx][el]);
    }
}

// phi expansion + bf16 copy of x
__global__ void phi_kernel(const float* __restrict__ x, u16* __restrict__ phi,
                           u16* __restrict__ xb) {
    int i = blockIdx.x * 256 + threadIdx.x;
    float xv = x[i];
    xb[i] = f2b(xv);
    u16x8 v;
#pragma unroll
    for (int k = 0; k < 8; ++k) {
        float s = -1.f + (2.f / 7.f) * (float)k;
        v[k] = f2b(sp(xv + s));
    }
    *(u16x8*)(phi + (size_t)i * 8) = v;
}

// GEMM1 partial, split-K=8 (kc pinned to XCD). 128x128 tile, BK=64.
// Partials stored bf16 in d_out scratch: xpart[kc][n][o].
// launch_bounds(256,3): ~170-reg class; acc(64)+frags(32)+addr fits, no spill.
__launch_bounds__(256, 3)
__global__ void gemm1p(const u16* __restrict__ phi, const u16* __restrict__ wphi,
                       u16* __restrict__ xpart) {
    __shared__ __align__(16) u16 lds[2 * 8192];   // 32 KB
    u16* As = lds;          // [128][64]
    u16* Bs = lds + 8192;

    const int id = blockIdx.x;
    const int kc = id & 7;                 // XCD-pinned K-chunk
    const int local = id >> 3;             // [0,128)
    const int o0 = (local & 3) * 128;
    const int n0 = (local >> 2) * 128;
    const int kbase = kc * 512;

    const int t = threadIdx.x;
    const int wave = t >> 6, lane = t & 63;
    const int wm = wave >> 1, wn = wave & 1;
    const int l15 = lane & 15, quad = lane >> 4;
    const int srow = t >> 3, scol = (t & 7) * 8;

    floatx4 acc[4][4];
#pragma unroll
    for (int i = 0; i < 4; ++i)
#pragma unroll
        for (int j = 0; j < 4; ++j) acc[i][j] = {0.f, 0.f, 0.f, 0.f};

    for (int k0 = 0; k0 < 512; k0 += 64) {
        const u16* ga = phi + (size_t)(n0 + srow) * 4096 + kbase + k0 + scol;
        const u16* gb = wphi + (size_t)(o0 + srow) * 4096 + kbase + k0 + scol;
        __syncthreads();
#pragma unroll
        for (int c = 0; c < 4; ++c) {
            gld16(ga + (size_t)c * 32 * 4096, As + c * 2048 + t * 8);
            gld16(gb + (size_t)c * 32 * 4096, Bs + c * 2048 + t * 8);
        }
        __syncthreads();
#pragma unroll
        for (int ks = 0; ks < 2; ++ks) {
            bf16x8 a[4], b[4];
#pragma unroll
            for (int s = 0; s < 4; ++s) {
                a[s] = *(const bf16x8*)(As + (wm * 64 + s * 16 + l15) * 64 + ks * 32 + quad * 8);
                b[s] = *(const bf16x8*)(Bs + (wn * 64 + s * 16 + l15) * 64 + ks * 32 + quad * 8);
            }
#pragma unroll
            for (int sm = 0; sm < 4; ++sm)
#pragma unroll
                for (int sn = 0; sn < 4; ++sn)
                    acc[sm][sn] = __builtin_amdgcn_mfma_f32_16x16x32_bf16(a[sm], b[sn], acc[sm][sn], 0, 0, 0);
        }
    }

    u16* xp = xpart + (size_t)kc * NTOK * DDOUT;
#pragma unroll
    for (int sm = 0; sm < 4; ++sm)
#pragma unroll
        for (int sn = 0; sn < 4; ++sn) {
            int gcol = o0 + wn * 64 + sn * 16 + l15;
#pragma unroll
            for (int r = 0; r < 4; ++r) {
                int grow = n0 + wm * 64 + sm * 16 + quad * 4 + r;
                xp[(size_t)grow * DDOUT + gcol] = f2b(acc[sm][sn][r]);
            }
        }
}

// reduce 8 bf16 partials + phi_bias, expand 8 gated softplus planes -> z0 (bf16)
__global__ void reduce_ep(const u16* __restrict__ xpart, const float* __restrict__ phi_bias,
                          const float* __restrict__ gate_raw, u16* __restrict__ z0) {
    int idx = blockIdx.x * 256 + threadIdx.x;      // 524288 threads, 4 elems each
    int n = idx >> 7;
    int o4 = (idx & 127) * 4;
    size_t base = (size_t)n * DDOUT + o4;
    float s0 = 0.f, s1 = 0.f, s2 = 0.f, s3 = 0.f;
#pragma unroll
    for (int kc = 0; kc < 8; ++kc) {
        u16x4 v = *(const u16x4*)(xpart + (size_t)kc * NTOK * DDOUT + base);
        s0 += b2f(v[0]); s1 += b2f(v[1]); s2 += b2f(v[2]); s3 += b2f(v[3]);
    }
    floatx4 pb = *(const floatx4*)(phi_bias + o4);
    s0 += pb[0]; s1 += pb[1]; s2 += pb[2]; s3 += pb[3];
#pragma unroll
    for (int p = 0; p < NP; ++p) {
        float g = sigm(gate_raw[p]);
        u16x4 v;
        v[0] = f2b(sp(s0 * g)); v[1] = f2b(sp(s1 * g));
        v[2] = f2b(sp(s2 * g)); v[3] = f2b(sp(s3 * g));
        *(u16x4*)(z0 + (size_t)p * NTOK * DDOUT + base) = v;
    }
}

// Fused GEMM2+GEMM3, 128x128 tile, BK=64, dual accumulators.
// Round-3 known-good config: 64 KB LDS, launch_bounds(256,2) -> 256-reg class,
// NO spill (round-4's (256,4) forced a 128-reg cap and spilled ~1.5 GB scratch).
// XCD-pinned: p = blockIdx.x & 7 keeps each plane's z0/w2/zwT in one XCD's L2.
__launch_bounds__(256, 2)
__global__ void gemm23(const u16* __restrict__ z0, const u16* __restrict__ w2b,
                       const u16* __restrict__ xb, const u16* __restrict__ zwT,
                       const float* __restrict__ bias2, const float* __restrict__ gate_raw2,
                       const float* __restrict__ output_bias, float* __restrict__ out) {
    __shared__ __align__(16) u16 lds[4 * 8192];   // 64 KB
    u16* A1 = lds;              // z0 tile [128][64]
    u16* B1 = lds + 8192;       // w2 tile
    u16* A2 = lds + 16384;      // xb tile
    u16* B2 = lds + 24576;      // zwT tile

    const int id = blockIdx.x;
    const int p = id & 7;
    const int local = id >> 3;                 // [0,128)
    const int e0 = (local & 3) * 128;
    const int n0 = (local >> 2) * 128;

    const int t = threadIdx.x;
    const int wave = t >> 6, lane = t & 63;
    const int wm = wave >> 1, wn = wave & 1;
    const int l15 = lane & 15, quad = lane >> 4;
    const int srow = t >> 3, scol = (t & 7) * 8;

    const u16* z0p = z0 + (size_t)p * NTOK * DDOUT;
    const u16* w2p = w2b + (size_t)p * DDOUT * DDOUT;
    const u16* zwp = zwT + (size_t)p * DDOUT * DDIN;

    floatx4 acc1[4][4], acc2[4][4];
#pragma unroll
    for (int i = 0; i < 4; ++i)
#pragma unroll
        for (int j = 0; j < 4; ++j) {
            acc1[i][j] = {0.f, 0.f, 0.f, 0.f};
            acc2[i][j] = {0.f, 0.f, 0.f, 0.f};
        }

    for (int k0 = 0; k0 < 512; k0 += 64) {
        const u16* ga1 = z0p + (size_t)(n0 + srow) * 512 + k0 + scol;
        const u16* gb1 = w2p + (size_t)(e0 + srow) * 512 + k0 + scol;
        const u16* ga2 = xb  + (size_t)(n0 + srow) * 512 + k0 + scol;
        const u16* gb2 = zwp + (size_t)(e0 + srow) * 512 + k0 + scol;
        __syncthreads();
#pragma unroll
        for (int c = 0; c < 4; ++c) {
            gld16(ga1 + (size_t)c * 32 * 512, A1 + c * 2048 + t * 8);
            gld16(gb1 + (size_t)c * 32 * 512, B1 + c * 2048 + t * 8);
            gld16(ga2 + (size_t)c * 32 * 512, A2 + c * 2048 + t * 8);
            gld16(gb2 + (size_t)c * 32 * 512, B2 + c * 2048 + t * 8);
        }
        __syncthreads();
#pragma unroll
        for (int ks = 0; ks < 2; ++ks) {
            bf16x8 a1[4], b1[4], a2[4], b2[4];
#pragma unroll
            for (int s = 0; s < 4; ++s) {
                int ro = (wm * 64 + s * 16 + l15) * 64 + ks * 32 + quad * 8;
                int co = (wn * 64 + s * 16 + l15) * 64 + ks * 32 + quad * 8;
                a1[s] = *(const bf16x8*)(A1 + ro);
                b1[s] = *(const bf16x8*)(B1 + co);
                a2[s] = *(const bf16x8*)(A2 + ro);
                b2[s] = *(const bf16x8*)(B2 + co);
            }
#pragma unroll
            for (int sm = 0; sm < 4; ++sm)
#pragma unroll
                for (int sn = 0; sn < 4; ++sn) {
                    acc1[sm][sn] = __builtin_amdgcn_mfma_f32_16x16x32_bf16(a1[sm], b1[sn], acc1[sm][sn], 0, 0, 0);
                    acc2[sm][sn] = __builtin_amdgcn_mfma_f32_16x16x32_bf16(a2[sm], b2[sn], acc2[sm][sn], 0, 0, 0);
                }
        }
    }

    const float g2p = sigm(gate_raw2[p]);
#pragma unroll
    for (int sm = 0; sm < 4; ++sm)
#pragma unroll
        for (int sn = 0; sn < 4; ++sn) {
            int gcol = e0 + wn * 64 + sn * 16 + l15;
            float bb = bias2[p * DDOUT + gcol];
            float ob = output_bias[p * DDOUT + gcol];
#pragma unroll
            for (int r = 0; r < 4; ++r) {
                int grow = n0 + wm * 64 + sm * 16 + quad * 4 + r;
                float v1 = acc1[sm][sn][r] + bb;
                float o = sp(sp(v1 * g2p) + acc2[sm][sn][r]) + ob;
                out[(size_t)grow * (NP * DDOUT) + p * DDOUT + gcol] = o;
            }
        }
}

extern "C" void kernel_launch(void* const* d_in, const int* in_sizes, int n_in,
                              void* d_out, int out_size, void* d_ws, size_t ws_size,
                              hipStream_t stream) {
    const float* x           = (const float*)d_in[0];
    const float* phi_raw     = (const float*)d_in[1];
    const float* phi_bias    = (const float*)d_in[2];
    const float* raw_weight2 = (const float*)d_in[3];
    const float* bias2       = (const float*)d_in[4];
    const float* gate_raw2   = (const float*)d_in[5];
    const float* z_weight    = (const float*)d_in[6];
    const float* gate_raw    = (const float*)d_in[7];
    const float* output_bias = (const float*)d_in[8];
    float* out = (float*)d_out;

    u16* ws   = (u16*)d_ws;
    u16* phi  = ws;                                  // 4096*4096 bf16
    u16* wphi = phi + (size_t)4096 * 4096;           // 512*4096
    u16* w2b  = wphi + (size_t)512 * 4096;           // 8*512*512
    u16* zwT  = w2b + (size_t)8 * 512 * 512;         // 8*512*512
    u16* z0   = zwT + (size_t)8 * 512 * 512;         // 8*4096*512
    u16* xb   = z0 + (size_t)8 * 4096 * 512;         // 4096*512
    // split-K=8 bf16 partials in d_out (33.5 MB of 67 MB), consumed by
    // reduce_ep before gemm23 overwrites d_out with the real fp32 output.
    u16* xpart = (u16*)d_out;

    const int n1 = 512 * 4096, n2 = 8 * 512 * 512;
    hipLaunchKernelGGL(prep_sqsp2, dim3((n1 + n2) / 256), dim3(256), 0, stream,
                       phi_raw, wphi, n1, raw_weight2, w2b, n2);
    hipLaunchKernelGGL(prep_zwT, dim3(16, 16, 8), dim3(32, 8), 0, stream, z_weight, zwT);
    hipLaunchKernelGGL(phi_kernel, dim3(8192), dim3(256), 0, stream, x, phi, xb);
    hipLaunchKernelGGL(gemm1p, dim3(1024), dim3(256), 0, stream, phi, wphi, xpart);
    hipLaunchKernelGGL(reduce_ep, dim3(2048), dim3(256), 0, stream, xpart, phi_bias, gate_raw, z0);
    hipLaunchKernelGGL(gemm23, dim3(1024), dim3(256), 0, stream,
                       z0, w2b, xb, zwT, bias2, gate_raw2, output_bias, out);
}

// Round 6
// 209.214 us; speedup vs baseline: 2.3806x; 1.0401x over previous
//
#include <hip/hip_runtime.h>

typedef unsigned short u16;
typedef __attribute__((ext_vector_type(8))) short bf16x8;     // MFMA A/B frag (8 bf16)
typedef __attribute__((ext_vector_type(4))) float floatx4;    // MFMA C/D frag
typedef __attribute__((ext_vector_type(8))) unsigned short u16x8;
typedef __attribute__((ext_vector_type(4))) unsigned short u16x4;

#define NTOK 4096
#define DDIN 512
#define DDOUT 512
#define NP 8

__device__ __forceinline__ float b2f(u16 b) {
    union { unsigned int u; float f; } v; v.u = ((unsigned int)b) << 16; return v.f;
}
__device__ __forceinline__ u16 f2b(float f) {
    union { float f; unsigned int u; } v; v.f = f;
    unsigned int r = (v.u + 0x7fffu + ((v.u >> 16) & 1u)) >> 16;
    return (u16)r;
}
__device__ __forceinline__ float sp(float x) {
    return fmaxf(x, 0.f) + __logf(1.f + __expf(-fabsf(x)));
}
__device__ __forceinline__ float sigm(float x) { return 1.f / (1.f + __expf(-x)); }

__device__ __forceinline__ void gld16(const u16* g, u16* l) {
    __builtin_amdgcn_global_load_lds((const __attribute__((address_space(1))) void*)g,
                                     (__attribute__((address_space(3))) void*)l, 16, 0, 0);
}

// weight transform for both phi_raw and raw_weight2 in one launch:
// out[i] = bf16( softplus(in[i])^2 )
__global__ void prep_sqsp2(const float* __restrict__ in1, u16* __restrict__ out1, int n1,
                           const float* __restrict__ in2, u16* __restrict__ out2, int n2) {
    int i = blockIdx.x * 256 + threadIdx.x;
    if (i < n1) {
        float s = sp(in1[i]);
        out1[i] = f2b(s * s);
    } else if (i - n1 < n2) {
        int j = i - n1;
        float s = sp(in2[j]);
        out2[j] = f2b(s * s);
    }
}

// zwT[p][e][c] = zw[p][c][e] + zw[p][c+512][e]
__global__ void prep_zwT(const float* __restrict__ zw, u16* __restrict__ zwT) {
    int p = blockIdx.z;
    int c0 = blockIdx.x * 32, e0 = blockIdx.y * 32;
    __shared__ float tb[32][33];
    int tx = threadIdx.x, ty = threadIdx.y; // 32 x 8
    const float* base = zw + (size_t)p * 1024 * 512;
#pragma unroll
    for (int r = 0; r < 4; ++r) {
        int cl = ty * 4 + r;
        float a = base[(size_t)(c0 + cl) * 512 + e0 + tx];
        float b = base[(size_t)(c0 + cl + 512) * 512 + e0 + tx];
        tb[cl][tx] = a + b;
    }
    __syncthreads();
    u16* outb = zwT + (size_t)p * 512 * 512;
#pragma unroll
    for (int r = 0; r < 4; ++r) {
        int el = ty * 4 + r;
        outb[(size_t)(e0 + el) * 512 + c0 + tx] = f2b(tb[tx][el]);
    }
}

// phi expansion + bf16 copy of x
__global__ void phi_kernel(const float* __restrict__ x, u16* __restrict__ phi,
                           u16* __restrict__ xb) {
    int i = blockIdx.x * 256 + threadIdx.x;
    float xv = x[i];
    xb[i] = f2b(xv);
    u16x8 v;
#pragma unroll
    for (int k = 0; k < 8; ++k) {
        float s = -1.f + (2.f / 7.f) * (float)k;
        v[k] = f2b(sp(xv + s));
    }
    *(u16x8*)(phi + (size_t)i * 8) = v;
}

// ---------------------------------------------------------------------------
// XOR k-group swizzle (bank-conflict fix, gld16-compatible):
// LDS row stride is 64 u16 = 128 B = 32 banks, so unswizzled fragment reads
// (16 lanes, consecutive rows, same k-offset) are ~16-way same-bank conflicts
// (measured 1.26e7 SQ_LDS_BANK_CONFLICT/dispatch in round 5). gld16 forbids
// LDS-side padding (lane-linear dests), so we permute the GLOBAL side:
// lane t stages global 16B-group (t&7)^((t>>3)&7) of row t>>3. Then
// LDS[r][g] = G[r][g^(r&7)], and frag reads at ((G)^(row&7)) spread the 8
// low lanes of each quad across all 32 banks (remaining duplication is
// 2-way = free). Global side stays contiguous per 8-lane cluster.
// ---------------------------------------------------------------------------

// GEMM1 partial, split-K=8 (kc pinned to XCD). 128x128 tile, BK=64.
// Partials stored bf16 in d_out scratch: xpart[kc][n][o].
__launch_bounds__(256, 3)
__global__ void gemm1p(const u16* __restrict__ phi, const u16* __restrict__ wphi,
                       u16* __restrict__ xpart) {
    __shared__ __align__(16) u16 lds[2 * 8192];   // 32 KB
    u16* As = lds;          // [128][64] swizzled
    u16* Bs = lds + 8192;

    const int id = blockIdx.x;
    const int kc = id & 7;                 // XCD-pinned K-chunk
    const int local = id >> 3;             // [0,128)
    const int o0 = (local & 3) * 128;
    const int n0 = (local >> 2) * 128;
    const int kbase = kc * 512;

    const int t = threadIdx.x;
    const int wave = t >> 6, lane = t & 63;
    const int wm = wave >> 1, wn = wave & 1;
    const int l15 = lane & 15, quad = lane >> 4;
    const int srow = t >> 3;
    const int sgx = (((t & 7) ^ (srow & 7))) * 8;   // swizzled global k-offset

    floatx4 acc[4][4];
#pragma unroll
    for (int i = 0; i < 4; ++i)
#pragma unroll
        for (int j = 0; j < 4; ++j) acc[i][j] = {0.f, 0.f, 0.f, 0.f};

    for (int k0 = 0; k0 < 512; k0 += 64) {
        const u16* ga = phi + (size_t)(n0 + srow) * 4096 + kbase + k0 + sgx;
        const u16* gb = wphi + (size_t)(o0 + srow) * 4096 + kbase + k0 + sgx;
        __syncthreads();
#pragma unroll
        for (int c = 0; c < 4; ++c) {
            gld16(ga + (size_t)c * 32 * 4096, As + c * 2048 + t * 8);
            gld16(gb + (size_t)c * 32 * 4096, Bs + c * 2048 + t * 8);
        }
        __syncthreads();
#pragma unroll
        for (int ks = 0; ks < 2; ++ks) {
            bf16x8 a[4], b[4];
#pragma unroll
            for (int s = 0; s < 4; ++s) {
                int ra = wm * 64 + s * 16 + l15;
                int rb = wn * 64 + s * 16 + l15;
                a[s] = *(const bf16x8*)(As + ra * 64 + (((ks * 4 + quad) ^ (ra & 7)) * 8));
                b[s] = *(const bf16x8*)(Bs + rb * 64 + (((ks * 4 + quad) ^ (rb & 7)) * 8));
            }
#pragma unroll
            for (int sm = 0; sm < 4; ++sm)
#pragma unroll
                for (int sn = 0; sn < 4; ++sn)
                    acc[sm][sn] = __builtin_amdgcn_mfma_f32_16x16x32_bf16(a[sm], b[sn], acc[sm][sn], 0, 0, 0);
        }
    }

    u16* xp = xpart + (size_t)kc * NTOK * DDOUT;
#pragma unroll
    for (int sm = 0; sm < 4; ++sm)
#pragma unroll
        for (int sn = 0; sn < 4; ++sn) {
            int gcol = o0 + wn * 64 + sn * 16 + l15;
#pragma unroll
            for (int r = 0; r < 4; ++r) {
                int grow = n0 + wm * 64 + sm * 16 + quad * 4 + r;
                xp[(size_t)grow * DDOUT + gcol] = f2b(acc[sm][sn][r]);
            }
        }
}

// reduce 8 bf16 partials + phi_bias, expand 8 gated softplus planes -> z0 (bf16)
__global__ void reduce_ep(const u16* __restrict__ xpart, const float* __restrict__ phi_bias,
                          const float* __restrict__ gate_raw, u16* __restrict__ z0) {
    int idx = blockIdx.x * 256 + threadIdx.x;      // 524288 threads, 4 elems each
    int n = idx >> 7;
    int o4 = (idx & 127) * 4;
    size_t base = (size_t)n * DDOUT + o4;
    float s0 = 0.f, s1 = 0.f, s2 = 0.f, s3 = 0.f;
#pragma unroll
    for (int kc = 0; kc < 8; ++kc) {
        u16x4 v = *(const u16x4*)(xpart + (size_t)kc * NTOK * DDOUT + base);
        s0 += b2f(v[0]); s1 += b2f(v[1]); s2 += b2f(v[2]); s3 += b2f(v[3]);
    }
    floatx4 pb = *(const floatx4*)(phi_bias + o4);
    s0 += pb[0]; s1 += pb[1]; s2 += pb[2]; s3 += pb[3];
#pragma unroll
    for (int p = 0; p < NP; ++p) {
        float g = sigm(gate_raw[p]);
        u16x4 v;
        v[0] = f2b(sp(s0 * g)); v[1] = f2b(sp(s1 * g));
        v[2] = f2b(sp(s2 * g)); v[3] = f2b(sp(s3 * g));
        *(u16x4*)(z0 + (size_t)p * NTOK * DDOUT + base) = v;
    }
}

// Fused GEMM2+GEMM3, 128x128 tile, BK=64, dual accumulators, swizzled LDS.
// 64 KB LDS, launch_bounds(256,2) -> 256-reg class, no spill.
// XCD-pinned: p = blockIdx.x & 7 keeps each plane's z0/w2/zwT in one XCD's L2.
__launch_bounds__(256, 2)
__global__ void gemm23(const u16* __restrict__ z0, const u16* __restrict__ w2b,
                       const u16* __restrict__ xb, const u16* __restrict__ zwT,
                       const float* __restrict__ bias2, const float* __restrict__ gate_raw2,
                       const float* __restrict__ output_bias, float* __restrict__ out) {
    __shared__ __align__(16) u16 lds[4 * 8192];   // 64 KB
    u16* A1 = lds;              // z0 tile [128][64] swizzled
    u16* B1 = lds + 8192;       // w2 tile
    u16* A2 = lds + 16384;      // xb tile
    u16* B2 = lds + 24576;      // zwT tile

    const int id = blockIdx.x;
    const int p = id & 7;
    const int local = id >> 3;                 // [0,128)
    const int e0 = (local & 3) * 128;
    const int n0 = (local >> 2) * 128;

    const int t = threadIdx.x;
    const int wave = t >> 6, lane = t & 63;
    const int wm = wave >> 1, wn = wave & 1;
    const int l15 = lane & 15, quad = lane >> 4;
    const int srow = t >> 3;
    const int sgx = (((t & 7) ^ (srow & 7))) * 8;   // swizzled global k-offset

    const u16* z0p = z0 + (size_t)p * NTOK * DDOUT;
    const u16* w2p = w2b + (size_t)p * DDOUT * DDOUT;
    const u16* zwp = zwT + (size_t)p * DDOUT * DDIN;

    floatx4 acc1[4][4], acc2[4][4];
#pragma unroll
    for (int i = 0; i < 4; ++i)
#pragma unroll
        for (int j = 0; j < 4; ++j) {
            acc1[i][j] = {0.f, 0.f, 0.f, 0.f};
            acc2[i][j] = {0.f, 0.f, 0.f, 0.f};
        }

    for (int k0 = 0; k0 < 512; k0 += 64) {
        const u16* ga1 = z0p + (size_t)(n0 + srow) * 512 + k0 + sgx;
        const u16* gb1 = w2p + (size_t)(e0 + srow) * 512 + k0 + sgx;
        const u16* ga2 = xb  + (size_t)(n0 + srow) * 512 + k0 + sgx;
        const u16* gb2 = zwp + (size_t)(e0 + srow) * 512 + k0 + sgx;
        __syncthreads();
#pragma unroll
        for (int c = 0; c < 4; ++c) {
            gld16(ga1 + (size_t)c * 32 * 512, A1 + c * 2048 + t * 8);
            gld16(gb1 + (size_t)c * 32 * 512, B1 + c * 2048 + t * 8);
            gld16(ga2 + (size_t)c * 32 * 512, A2 + c * 2048 + t * 8);
            gld16(gb2 + (size_t)c * 32 * 512, B2 + c * 2048 + t * 8);
        }
        __syncthreads();
#pragma unroll
        for (int ks = 0; ks < 2; ++ks) {
            bf16x8 a1[4], b1[4], a2[4], b2[4];
#pragma unroll
            for (int s = 0; s < 4; ++s) {
                int ra = wm * 64 + s * 16 + l15;
                int rb = wn * 64 + s * 16 + l15;
                int ko = ((ks * 4 + quad) ^ (ra & 7)) * 8;   // ra&7 == rb&7 == l15&7
                a1[s] = *(const bf16x8*)(A1 + ra * 64 + ko);
                b1[s] = *(const bf16x8*)(B1 + rb * 64 + ko);
                a2[s] = *(const bf16x8*)(A2 + ra * 64 + ko);
                b2[s] = *(const bf16x8*)(B2 + rb * 64 + ko);
            }
#pragma unroll
            for (int sm = 0; sm < 4; ++sm)
#pragma unroll
                for (int sn = 0; sn < 4; ++sn) {
                    acc1[sm][sn] = __builtin_amdgcn_mfma_f32_16x16x32_bf16(a1[sm], b1[sn], acc1[sm][sn], 0, 0, 0);
                    acc2[sm][sn] = __builtin_amdgcn_mfma_f32_16x16x32_bf16(a2[sm], b2[sn], acc2[sm][sn], 0, 0, 0);
                }
        }
    }

    const float g2p = sigm(gate_raw2[p]);
#pragma unroll
    for (int sm = 0; sm < 4; ++sm)
#pragma unroll
        for (int sn = 0; sn < 4; ++sn) {
            int gcol = e0 + wn * 64 + sn * 16 + l15;
            float bb = bias2[p * DDOUT + gcol];
            float ob = output_bias[p * DDOUT + gcol];
#pragma unroll
            for (int r = 0; r < 4; ++r) {
                int grow = n0 + wm * 64 + sm * 16 + quad * 4 + r;
                float v1 = acc1[sm][sn][r] + bb;
                float o = sp(sp(v1 * g2p) + acc2[sm][sn][r]) + ob;
                out[(size_t)grow * (NP * DDOUT) + p * DDOUT + gcol] = o;
            }
        }
}

extern "C" void kernel_launch(void* const* d_in, const int* in_sizes, int n_in,
                              void* d_out, int out_size, void* d_ws, size_t ws_size,
                              hipStream_t stream) {
    const float* x           = (const float*)d_in[0];
    const float* phi_raw     = (const float*)d_in[1];
    const float* phi_bias    = (const float*)d_in[2];
    const float* raw_weight2 = (const float*)d_in[3];
    const float* bias2       = (const float*)d_in[4];
    const float* gate_raw2   = (const float*)d_in[5];
    const float* z_weight    = (const float*)d_in[6];
    const float* gate_raw    = (const float*)d_in[7];
    const float* output_bias = (const float*)d_in[8];
    float* out = (float*)d_out;

    u16* ws   = (u16*)d_ws;
    u16* phi  = ws;                                  // 4096*4096 bf16
    u16* wphi = phi + (size_t)4096 * 4096;           // 512*4096
    u16* w2b  = wphi + (size_t)512 * 4096;           // 8*512*512
    u16* zwT  = w2b + (size_t)8 * 512 * 512;         // 8*512*512
    u16* z0   = zwT + (size_t)8 * 512 * 512;         // 8*4096*512
    u16* xb   = z0 + (size_t)8 * 4096 * 512;         // 4096*512
    // split-K=8 bf16 partials in d_out (33.5 MB of 67 MB), consumed by
    // reduce_ep before gemm23 overwrites d_out with the real fp32 output.
    u16* xpart = (u16*)d_out;

    const int n1 = 512 * 4096, n2 = 8 * 512 * 512;
    hipLaunchKernelGGL(prep_sqsp2, dim3((n1 + n2) / 256), dim3(256), 0, stream,
                       phi_raw, wphi, n1, raw_weight2, w2b, n2);
    hipLaunchKernelGGL(prep_zwT, dim3(16, 16, 8), dim3(32, 8), 0, stream, z_weight, zwT);
    hipLaunchKernelGGL(phi_kernel, dim3(8192), dim3(256), 0, stream, x, phi, xb);
    hipLaunchKernelGGL(gemm1p, dim3(1024), dim3(256), 0, stream, phi, wphi, xpart);
    hipLaunchKernelGGL(reduce_ep, dim3(2048), dim3(256), 0, stream, xpart, phi_bias, gate_raw, z0);
    hipLaunchKernelGGL(gemm23, dim3(1024), dim3(256), 0, stream,
                       z0, w2b, xb, zwT, bias2, gate_raw2, output_bias, out);
}